// Round 12
// baseline (423.168 us; speedup 1.0000x reference)
//
#include <hip/hip_runtime.h>

#define AB 513
#define TD 263169   // 513*513
#define TILE 16416  // 32 rows * 513 floats, contiguous in W

typedef float f4 __attribute__((ext_vector_type(4)));
typedef float f32x4 __attribute__((ext_vector_type(4)));
typedef short bf16x8 __attribute__((ext_vector_type(8)));
typedef int i32x4 __attribute__((ext_vector_type(4)));
#define GAS __attribute__((address_space(1)))
#define LAS __attribute__((address_space(3)))

// ---------------------------------------------------------------------------
// Kernel 1a: pool over S. Blocks 0..63 = vision bt, 64..127 = audio bt.
// ---------------------------------------------------------------------------
__global__ __launch_bounds__(256) void pool_kernel(
    const float* __restrict__ vx, const float* __restrict__ ax,
    float* __restrict__ pvT, float* __restrict__ paT)
{
    const int isA = (blockIdx.x >= 64);
    const int bt = blockIdx.x & 63;
    const float* x = isA ? ax : vx;
    float* pT = isA ? paT : pvT;
    const int D = isA ? 512 : 768;
    const int nd4 = D >> 2;
    const int tid = threadIdx.x;
    if (tid < nd4) {
        f4 s0 = {0.f, 0.f, 0.f, 0.f}, s1 = s0, s2 = s0, s3 = s0;
        const float* xp = x + (size_t)bt * 64 * D + tid * 4;
        #pragma unroll 4
        for (int ss = 0; ss < 64; ss += 4) {
            s0 += *(const f4*)(xp + (size_t)ss * D);
            s1 += *(const f4*)(xp + (size_t)(ss + 1) * D);
            s2 += *(const f4*)(xp + (size_t)(ss + 2) * D);
            s3 += *(const f4*)(xp + (size_t)(ss + 3) * D);
        }
        const f4 s = ((s0 + s1) + (s2 + s3)) * 0.015625f;
        #pragma unroll
        for (int q = 0; q < 4; ++q) pT[(tid * 4 + q) * 64 + bt] = s[q];
    }
}

// ---------------------------------------------------------------------------
// Kernel 1b: layer1, weight-stationary. Block = 8-h tile; wave = h row.
// ---------------------------------------------------------------------------
__global__ __launch_bounds__(512) void mlp1_kernel(
    const float* __restrict__ pvT, const float* __restrict__ paT,
    const float* __restrict__ vw1, const float* __restrict__ vb1,
    const float* __restrict__ aw1, const float* __restrict__ ab1,
    float* __restrict__ h1vT, float* __restrict__ h1aT)
{
    const int isA = (blockIdx.x >= 64);
    const int D = isA ? 512 : 768;
    const float* pT = isA ? paT : pvT;
    const float* w1 = isA ? aw1 : vw1;
    const float* b1 = isA ? ab1 : vb1;
    float* h1T = isA ? h1aT : h1vT;
    const int tid = threadIdx.x, lane = tid & 63, w = tid >> 6;
    const int h = (blockIdx.x & 63) * 8 + w;
    const float* wr = w1 + (size_t)h * D;

    float a0 = 0.f, a1 = 0.f, a2 = 0.f, a3 = 0.f;
    for (int d = 0; d < D; d += 16) {
        const f4 w0 = *(const f4*)(wr + d);
        const f4 w1v = *(const f4*)(wr + d + 4);
        const f4 w2v = *(const f4*)(wr + d + 8);
        const f4 w3v = *(const f4*)(wr + d + 12);
        #pragma unroll
        for (int q = 0; q < 4; ++q) {
            a0 = fmaf(w0[q],  pT[(d + q) * 64 + lane], a0);
            a1 = fmaf(w1v[q], pT[(d + 4 + q) * 64 + lane], a1);
            a2 = fmaf(w2v[q], pT[(d + 8 + q) * 64 + lane], a2);
            a3 = fmaf(w3v[q], pT[(d + 12 + q) * 64 + lane], a3);
        }
    }
    h1T[h * 64 + lane] = fmaxf((a0 + a1) + (a2 + a3) + b1[h], 0.f);
}

// ---------------------------------------------------------------------------
// Kernel 1c: layer2 (no relu) + trailing ones row.
// ---------------------------------------------------------------------------
__global__ __launch_bounds__(512) void mlp2_kernel(
    const float* __restrict__ h1vT, const float* __restrict__ h1aT,
    const float* __restrict__ vw2, const float* __restrict__ vb2,
    const float* __restrict__ aw2, const float* __restrict__ ab2,
    float* __restrict__ aTout, float* __restrict__ bTout)
{
    const int isA = (blockIdx.x >= 64);
    const float* hT = isA ? h1aT : h1vT;
    const float* w2 = isA ? aw2 : vw2;
    const float* b2 = isA ? ab2 : vb2;
    float* outT = isA ? bTout : aTout;
    const int tid = threadIdx.x, lane = tid & 63, w = tid >> 6;
    const int h = (blockIdx.x & 63) * 8 + w;
    const float* wr = w2 + (size_t)h * 512;

    float a0 = 0.f, a1 = 0.f, a2 = 0.f, a3 = 0.f;
    for (int d = 0; d < 512; d += 16) {
        const f4 w0 = *(const f4*)(wr + d);
        const f4 w1v = *(const f4*)(wr + d + 4);
        const f4 w2v = *(const f4*)(wr + d + 8);
        const f4 w3v = *(const f4*)(wr + d + 12);
        #pragma unroll
        for (int q = 0; q < 4; ++q) {
            a0 = fmaf(w0[q],  hT[(d + q) * 64 + lane], a0);
            a1 = fmaf(w1v[q], hT[(d + 4 + q) * 64 + lane], a1);
            a2 = fmaf(w2v[q], hT[(d + 8 + q) * 64 + lane], a2);
            a3 = fmaf(w3v[q], hT[(d + 12 + q) * 64 + lane], a3);
        }
    }
    outT[h * 64 + lane] = (a0 + a1) + (a2 + a3) + b2[h];
    if ((blockIdx.x & 63) == 0 && tid < 64) outT[512 * 64 + tid] = 1.0f;
}

// ---------------------------------------------------------------------------
// Kernel 1d: split aT into 3 truncated-bf16 levels in MFMA A-fragment order.
// ---------------------------------------------------------------------------
__global__ __launch_bounds__(256) void aprep_kernel(
    const float* __restrict__ aT,   // (513, 64)
    short* __restrict__ aF1, short* __restrict__ aF2, short* __restrict__ aF3)
{
    const int t = blockIdx.x * 256 + threadIdx.x;  // [0, 4096)
    const int l = t & 63, mt = (t >> 6) & 3, kt = t >> 8;
    const int m = mt * 16 + (l & 15);
    const int kbase = kt * 32 + ((l >> 4) << 3);
    const int obase = ((kt * 4 + mt) * 64 + l) * 8;
    #pragma unroll
    for (int i = 0; i < 8; ++i) {
        const float v = aT[(size_t)(kbase + i) * 64 + m];
        const unsigned u = __float_as_uint(v);
        const float r1 = v - __uint_as_float(u & 0xFFFF0000u);
        const unsigned u1 = __float_as_uint(r1);
        const float r2 = r1 - __uint_as_float(u1 & 0xFFFF0000u);
        const unsigned u2 = __float_as_uint(r2);
        aF1[obase + i] = (short)(u >> 16);
        aF2[obase + i] = (short)(u1 >> 16);
        aF3[obase + i] = (short)(u2 >> 16);
    }
}

// ---------------------------------------------------------------------------
// Kernel 2: bilinear via bf16-split MFMA (verified math), CONTIGUOUS-STREAM
// cooperative staging. A K-step tile = 32 rows * 513 = 16416 consecutive
// floats of W (zero overfetch, fully coalesced, aligned bursts). Tile is
// double-buffered in LDS; all 8 waves stage cooperatively (wave w covers
// floats [w*2048, w*2048+2048) via 8 width-16 DMA + one width-4 remainder
// sweep). T3/T4 schedule per epoch:
//   wait vmcnt(9)  [drains tile kt + A(kt); tile kt+1 stays in flight]
//   s_barrier; LOADA(kt+1); COMPUTE(kt); s_barrier; STAGE(kt+2)
// B-read idx = row*513 + e: 513 odd => banks self-swizzled (2-way = free).
// ---------------------------------------------------------------------------
__global__ __launch_bounds__(512, 1) void bilinear_kernel(
    const float* __restrict__ fw1,  // (1024, 263169)
    const float* __restrict__ fb1,  // (1024)
    const float* __restrict__ aT,   // (513, 64)
    const float* __restrict__ bT,   // (513, 64)
    const short* __restrict__ aF1, const short* __restrict__ aF2,
    const short* __restrict__ aF3,
    float* __restrict__ hbufT)      // (1024, 64)
{
    __shared__ float lds[33344];  // buf0[16448] | buf1[16448] | dump[448]
    float* const buf0 = lds;
    float* const buf1 = lds + 16448;
    float* const ldsdump = lds + 32896;

    const int tid = threadIdx.x;
    const int l = tid & 63, w = tid >> 6;
    const int o = blockIdx.x;
    const float* __restrict__ W = fw1 + (size_t)o * TD;
    const int we0 = w * 64;
    const int lq = l >> 4, ln = l & 15;

    // tile c = W floats [c*16416, (c+1)*16416); 9 DMA instrs per wave
    #define STAGE(bufb_, c_)                                                   \
        do {                                                                   \
            const float* csrc_ = W + (size_t)(c_) * TILE;                      \
            _Pragma("unroll")                                                  \
            for (int is_ = 0; is_ < 8; ++is_) {                                \
                __builtin_amdgcn_global_load_lds(                              \
                    (const GAS unsigned*)(const void*)(csrc_ + w * 2048 + is_ * 256 + l * 4), \
                    (LAS unsigned*)(void*)((bufb_) + w * 2048 + is_ * 256), 16, 0, 0); \
            }                                                                  \
            {   /* remainder floats 16384..16415 (wave0); others -> dump */    \
                const float* rs_ = csrc_ + 16384 + (l & 31);                   \
                float* rd_ = (w == 0) ? ((bufb_) + 16384) : (ldsdump + (w - 1) * 64); \
                __builtin_amdgcn_global_load_lds(                              \
                    (const GAS unsigned*)(const void*)rs_,                     \
                    (LAS unsigned*)(void*)rd_, 4, 0, 0);                       \
            }                                                                  \
        } while (0)

    #define LOADA(A1r, A2r, A3r, kt_)                                          \
        do {                                                                   \
            _Pragma("unroll")                                                  \
            for (int mt_ = 0; mt_ < 4; ++mt_) {                                \
                const int fb_ = (((kt_) * 4 + mt_) * 64 + l) * 8;              \
                A1r[mt_] = *(const bf16x8*)(aF1 + fb_);                        \
                A2r[mt_] = *(const bf16x8*)(aF2 + fb_);                        \
                A3r[mt_] = *(const bf16x8*)(aF3 + fb_);                        \
            }                                                                  \
        } while (0)

    #define COMPUTE(wb_, A1r, A2r, A3r)                                        \
        do {                                                                   \
            _Pragma("unroll")                                                  \
            for (int nt = 0; nt < 4; ++nt) {                                   \
                unsigned u0[8], u1[8], u2[8];                                  \
                _Pragma("unroll")                                              \
                for (int i = 0; i < 8; ++i) {                                  \
                    const float v = (wb_)[(lq * 8 + i) * 513 + we0 + nt * 16 + ln]; \
                    u0[i] = __float_as_uint(v);                                \
                    const float r1 = v - __uint_as_float(u0[i] & 0xFFFF0000u); \
                    u1[i] = __float_as_uint(r1);                               \
                    const float r2 = r1 - __uint_as_float(u1[i] & 0xFFFF0000u);\
                    u2[i] = __float_as_uint(r2);                               \
                }                                                              \
                i32x4 p1, p2, p3;                                              \
                _Pragma("unroll")                                              \
                for (int j = 0; j < 4; ++j) {                                  \
                    p1[j] = (int)((u0[2 * j + 1] & 0xFFFF0000u) | (u0[2 * j] >> 16)); \
                    p2[j] = (int)((u1[2 * j + 1] & 0xFFFF0000u) | (u1[2 * j] >> 16)); \
                    p3[j] = (int)((u2[2 * j + 1] & 0xFFFF0000u) | (u2[2 * j] >> 16)); \
                }                                                              \
                const bf16x8 B1 = __builtin_bit_cast(bf16x8, p1);              \
                const bf16x8 B2 = __builtin_bit_cast(bf16x8, p2);              \
                const bf16x8 B3 = __builtin_bit_cast(bf16x8, p3);              \
                _Pragma("unroll")                                              \
                for (int mt = 0; mt < 4; ++mt) {                               \
                    acc[mt][nt] = __builtin_amdgcn_mfma_f32_16x16x32_bf16(A1r[mt], B1, acc[mt][nt], 0, 0, 0); \
                    acc[mt][nt] = __builtin_amdgcn_mfma_f32_16x16x32_bf16(A1r[mt], B2, acc[mt][nt], 0, 0, 0); \
                    acc[mt][nt] = __builtin_amdgcn_mfma_f32_16x16x32_bf16(A2r[mt], B1, acc[mt][nt], 0, 0, 0); \
                    acc[mt][nt] = __builtin_amdgcn_mfma_f32_16x16x32_bf16(A2r[mt], B2, acc[mt][nt], 0, 0, 0); \
                    acc[mt][nt] = __builtin_amdgcn_mfma_f32_16x16x32_bf16(A1r[mt], B3, acc[mt][nt], 0, 0, 0); \
                    acc[mt][nt] = __builtin_amdgcn_mfma_f32_16x16x32_bf16(A3r[mt], B1, acc[mt][nt], 0, 0, 0); \
                }                                                              \
            }                                                                  \
        } while (0)

    f32x4 acc[4][4];
    #pragma unroll
    for (int mt = 0; mt < 4; ++mt)
        #pragma unroll
        for (int nt = 0; nt < 4; ++nt)
            acc[mt][nt] = (f32x4){0.f, 0.f, 0.f, 0.f};

    bf16x8 Aa1[4], Aa2[4], Aa3[4], Ab1[4], Ab2[4], Ab3[4];

    // prologue: stage(0)[9], A(0)[12], stage(1)[9] -> 30 outstanding.
    // epoch-0 wait vmcnt(9) drains stage(0)+A(0), leaves stage(1).
    STAGE(buf0, 0);
    LOADA(Aa1, Aa2, Aa3, 0);
    STAGE(buf1, 1);

    #pragma unroll 1
    for (int it = 0; it < 7; ++it) {        // kt = 2it, 2it+1  (0..13)
        asm volatile("s_waitcnt vmcnt(9)" ::: "memory");
        __builtin_amdgcn_s_barrier();
        LOADA(Ab1, Ab2, Ab3, 2 * it + 1);
        COMPUTE(buf0, Aa1, Aa2, Aa3);
        __builtin_amdgcn_s_barrier();
        STAGE(buf0, 2 * it + 2);

        asm volatile("s_waitcnt vmcnt(9)" ::: "memory");
        __builtin_amdgcn_s_barrier();
        LOADA(Aa1, Aa2, Aa3, 2 * it + 2);
        COMPUTE(buf1, Ab1, Ab2, Ab3);
        __builtin_amdgcn_s_barrier();
        STAGE(buf1, 2 * it + 3);
    }
    // kt = 14 (buf0, Aa): load A(15); no stage(16)
    asm volatile("s_waitcnt vmcnt(9)" ::: "memory");
    __builtin_amdgcn_s_barrier();
    LOADA(Ab1, Ab2, Ab3, 15);
    COMPUTE(buf0, Aa1, Aa2, Aa3);
    __builtin_amdgcn_s_barrier();
    // kt = 15 (buf1, Ab): full drain
    asm volatile("s_waitcnt vmcnt(0)" ::: "memory");
    __builtin_amdgcn_s_barrier();
    COMPUTE(buf1, Ab1, Ab2, Ab3);
    // no DMA in flight; buf0 free after the barrier below -> red storage.

    // y[bt] = sum_e P[bt,e] * b[e,bt] over this wave's e-range.
    // P fragment: bt = mt*16 + lq*4 + r, e = we0 + nt*16 + ln.
    float ysum[4][4];
    #pragma unroll
    for (int mt = 0; mt < 4; ++mt)
        #pragma unroll
        for (int r = 0; r < 4; ++r) ysum[mt][r] = 0.f;
    #pragma unroll
    for (int mt = 0; mt < 4; ++mt) {
        const int bt0 = mt * 16 + lq * 4;
        #pragma unroll
        for (int nt = 0; nt < 4; ++nt) {
            const int e = we0 + nt * 16 + ln;
            const f4 bv = *(const f4*)(bT + (size_t)e * 64 + bt0);
            #pragma unroll
            for (int r = 0; r < 4; ++r)
                ysum[mt][r] = fmaf(acc[mt][nt][r], bv[r], ysum[mt][r]);
        }
    }
    #pragma unroll
    for (int mt = 0; mt < 4; ++mt)
        #pragma unroll
        for (int r = 0; r < 4; ++r) {
            float v = ysum[mt][r];
            v += __shfl_xor(v, 1, 64);
            v += __shfl_xor(v, 2, 64);
            v += __shfl_xor(v, 4, 64);
            v += __shfl_xor(v, 8, 64);
            ysum[mt][r] = v;
        }
    __syncthreads();  // everyone past COMPUTE(15)'s buf1 reads; buf0 dead
    if (ln == 0) {
        #pragma unroll
        for (int mt = 0; mt < 4; ++mt)
            #pragma unroll
            for (int r = 0; r < 4; ++r)
                buf0[w * 64 + mt * 16 + lq * 4 + r] = ysum[mt][r];  // red_main
    }

    // aux: e=512 col (b==1) + d=512 row (a==1), wave's 64-range; lane = bt
    {
        float s0 = 0.f, s1 = 0.f, s2 = 0.f, s3 = 0.f;
        #pragma unroll 4
        for (int k = 0; k < 64; k += 4) {
            s0 = fmaf(aT[(size_t)(we0 + k) * 64 + l], W[(size_t)(we0 + k) * AB + 512], s0);
            s1 = fmaf(aT[(size_t)(we0 + k + 1) * 64 + l], W[(size_t)(we0 + k + 1) * AB + 512], s1);
            s2 = fmaf(aT[(size_t)(we0 + k + 2) * 64 + l], W[(size_t)(we0 + k + 2) * AB + 512], s2);
            s3 = fmaf(aT[(size_t)(we0 + k + 3) * 64 + l], W[(size_t)(we0 + k + 3) * AB + 512], s3);
        }
        #pragma unroll 4
        for (int k = 0; k < 64; k += 4) {
            s0 = fmaf(W[(size_t)512 * AB + we0 + k], bT[(size_t)(we0 + k) * 64 + l], s0);
            s1 = fmaf(W[(size_t)512 * AB + we0 + k + 1], bT[(size_t)(we0 + k + 1) * 64 + l], s1);
            s2 = fmaf(W[(size_t)512 * AB + we0 + k + 2], bT[(size_t)(we0 + k + 2) * 64 + l], s2);
            s3 = fmaf(W[(size_t)512 * AB + we0 + k + 3], bT[(size_t)(we0 + k + 3) * 64 + l], s3);
        }
        buf0[512 + w * 64 + l] = (s0 + s1) + (s2 + s3);  // red_aux
    }

    __syncthreads();

    if (w == 0) {
        float t2 = 0.f;
        #pragma unroll
        for (int k = 0; k < 8; ++k)
            t2 += buf0[k * 64 + l] + buf0[512 + k * 64 + l];
        t2 += W[(size_t)512 * AB + 512] + fb1[o];  // corner (a=b=1)
        hbufT[(size_t)o * 64 + l] = fmaxf(t2, 0.f);
    }
    #undef STAGE
    #undef LOADA
    #undef COMPUTE
}

// ---------------------------------------------------------------------------
// Kernel 3a: fused[bt, f] = h[bt, :] @ fw2[f, :] + fb2[f].
// ---------------------------------------------------------------------------
__global__ __launch_bounds__(512) void fuse2_kernel(
    const float* __restrict__ hbufT,  // (1024, 64)
    const float* __restrict__ fw2,    // (512, 1024)
    const float* __restrict__ fb2,    // (512)
    float* __restrict__ fused)        // (64, 512)
{
    const int tid = threadIdx.x, lane = tid & 63, w = tid >> 6;
    #pragma unroll
    for (int k = 0; k < 2; ++k) {
        const int f = blockIdx.x * 16 + w * 2 + k;
        const float* wr = fw2 + (size_t)f * 1024;
        float a0 = 0.f, a1 = 0.f, a2 = 0.f, a3 = 0.f;
        for (int o = 0; o < 1024; o += 16) {
            const f4 w0 = *(const f4*)(wr + o);
            const f4 w1v = *(const f4*)(wr + o + 4);
            const f4 w2v = *(const f4*)(wr + o + 8);
            const f4 w3v = *(const f4*)(wr + o + 12);
            #pragma unroll
            for (int q = 0; q < 4; ++q) {
                a0 = fmaf(w0[q],  hbufT[(o + q) * 64 + lane], a0);
                a1 = fmaf(w1v[q], hbufT[(o + 4 + q) * 64 + lane], a1);
                a2 = fmaf(w2v[q], hbufT[(o + 8 + q) * 64 + lane], a2);
                a3 = fmaf(w3v[q], hbufT[(o + 12 + q) * 64 + lane], a3);
            }
        }
        fused[lane * 512 + f] = (a0 + a1) + (a2 + a3) + fb2[f];
    }
}

// ---------------------------------------------------------------------------
// Kernel 3b: LIF over time. 1024 independent (b, d) chains, T = 32.
// ---------------------------------------------------------------------------
__global__ __launch_bounds__(256) void lif_kernel(
    const float* __restrict__ fused,  // (2, 32, 512)
    float* __restrict__ out)          // (2, 32, 512)
{
    const int idx = blockIdx.x * 256 + threadIdx.x;
    if (idx >= 1024) return;
    const int b = idx >> 9, dd = idx & 511;
    float mem = 0.f;
    for (int t = 0; t < 32; ++t) {
        const size_t off = ((size_t)(b * 32 + t) * 512) + dd;
        mem = 0.9f * mem + fused[off];
        const float s = (mem >= 1.0f) ? 1.0f : 0.0f;
        out[off] = s;
        mem -= s;
    }
}

// ---------------------------------------------------------------------------
extern "C" void kernel_launch(void* const* d_in, const int* in_sizes, int n_in,
                              void* d_out, int out_size, void* d_ws, size_t ws_size,
                              hipStream_t stream) {
    const float* vision = (const float*)d_in[0];
    const float* audio  = (const float*)d_in[1];
    const float* vw1 = (const float*)d_in[2];
    const float* vb1 = (const float*)d_in[3];
    const float* vw2 = (const float*)d_in[4];
    const float* vb2 = (const float*)d_in[5];
    const float* aw1 = (const float*)d_in[6];
    const float* ab1 = (const float*)d_in[7];
    const float* aw2 = (const float*)d_in[8];
    const float* ab2 = (const float*)d_in[9];
    const float* fw1 = (const float*)d_in[10];
    const float* fb1 = (const float*)d_in[11];
    const float* fw2 = (const float*)d_in[12];
    const float* fb2 = (const float*)d_in[13];
    float* out = (float*)d_out;

    float* ws    = (float*)d_ws;
    float* pvT   = ws;                  // 768*64
    float* paT   = pvT + 768 * 64;      // 512*64
    float* h1vT  = paT + 512 * 64;      // 512*64
    float* h1aT  = h1vT + 512 * 64;     // 512*64
    float* aT    = h1aT + 512 * 64;     // 513*64
    float* bT    = aT + AB * 64;        // 513*64
    float* hbufT = bT + AB * 64;        // 1024*64
    float* fused = hbufT + 1024 * 64;   // 64*512
    short* aF1   = (short*)(fused + 64 * 512);  // 32768 shorts
    short* aF2   = aF1 + 32768;
    short* aF3   = aF2 + 32768;

    pool_kernel<<<128, 256, 0, stream>>>(vision, audio, pvT, paT);
    mlp1_kernel<<<128, 512, 0, stream>>>(pvT, paT, vw1, vb1, aw1, ab1, h1vT, h1aT);
    mlp2_kernel<<<128, 512, 0, stream>>>(h1vT, h1aT, vw2, vb2, aw2, ab2, aT, bT);
    aprep_kernel<<<16, 256, 0, stream>>>(aT, aF1, aF2, aF3);
    bilinear_kernel<<<1024, 512, 0, stream>>>(fw1, fb1, aT, bT, aF1, aF2, aF3, hbufT);
    fuse2_kernel<<<32, 512, 0, stream>>>(hbufT, fw2, fb2, fused);
    lif_kernel<<<4, 256, 0, stream>>>(fused, out);
}